// Round 13
// baseline (447.473 us; speedup 1.0000x reference)
//
#include <hip/hip_runtime.h>

#define NN 40000
#define NE 640000
#define HID 128
#define SCAN_BLK ((NN + 255) / 256)   // 157
#define CAP 1024                      // staged edge-indices per chunk

typedef __attribute__((ext_vector_type(8)))  short short8;
typedef __attribute__((ext_vector_type(4)))  short short4v;
typedef __attribute__((ext_vector_type(16))) float floatx16;
typedef unsigned int uint;

__device__ __forceinline__ short f2bf(float f) {
    union { float f; unsigned u; } c; c.f = f;
    unsigned u = c.u;
    unsigned r = (u + 0x7FFF + ((u >> 16) & 1)) >> 16;   // RNE
    return (short)r;
}
__device__ __forceinline__ float bf2f(short h) {
    union { unsigned u; float f; } c;
    c.u = ((unsigned)(unsigned short)h) << 16;
    return c.f;
}
__device__ __forceinline__ float asf(uint u) {
    union { uint u; float f; } c; c.u = u; return c.f;
}
// Packed split-bf16: u32 = (hi_bf16 << 16) | lo_bf16; hi+lo ~ x to ~2^-17 rel.
__device__ __forceinline__ uint packsplit(float f) {
    short h = f2bf(f);
    short l = f2bf(f - bf2f(h));
    return ((uint)(unsigned short)h << 16) | (uint)(unsigned short)l;
}
__device__ __forceinline__ float unpackf(uint u) {
    return asf(u & 0xFFFF0000u) + asf(u << 16);
}
__device__ __forceinline__ void unpack8(uint4 a, uint4 b, short8* h, short8* l) {
    short8 H, L;
    H[0] = (short)(a.x >> 16); L[0] = (short)a.x;
    H[1] = (short)(a.y >> 16); L[1] = (short)a.y;
    H[2] = (short)(a.z >> 16); L[2] = (short)a.z;
    H[3] = (short)(a.w >> 16); L[3] = (short)a.w;
    H[4] = (short)(b.x >> 16); L[4] = (short)b.x;
    H[5] = (short)(b.y >> 16); L[5] = (short)b.y;
    H[6] = (short)(b.z >> 16); L[6] = (short)b.z;
    H[7] = (short)(b.w >> 16); L[7] = (short)b.w;
    *h = H; *l = L;
}

// W fragment swizzle (HW-verified r9-r12): element (o,k) of [128][WS] row-major
// -> index so a wave's B-load is base + lane*8 uints (coalesced).
__device__ __forceinline__ int wswz(int o, int k) {
    int chunk = k >> 4, half = (k >> 3) & 1, j = k & 7;
    int ct = o >> 5, m31 = o & 31;
    int lane = half * 32 + m31;
    return (((chunk * 4 + ct) * 64 + lane) * 8 + j);
}

#define ACCP(u, H, L)                                            \
    H.x += asf(u.x & 0xFFFF0000u); L.x += asf(u.x << 16);        \
    H.y += asf(u.y & 0xFFFF0000u); L.y += asf(u.y << 16);        \
    H.z += asf(u.z & 0xFFFF0000u); L.z += asf(u.z << 16);        \
    H.w += asf(u.w & 0xFFFF0000u); L.w += asf(u.w << 16);

// ---------------- fused gather + split-bf16 MFMA linear ---------------------
// out[n][:] = relu( W · (sum_{e: dst=n} h[src[e]]) + b ), 32 nodes per block.
// Edge indices staged to LDS (chunked, uniform barriers) -> row loads have no
// VMEM dependence; 8 independent row loads in flight per lane-group.
__global__ __launch_bounds__(256, 4) void fused_gather_lin_kernel(
    const uint* __restrict__ h, const int* __restrict__ row_ptr,
    const int* __restrict__ esrc, const uint* __restrict__ Wq,
    const float* __restrict__ bias, uint* __restrict__ out)
{
    __shared__ short sAh[4096];
    __shared__ short sAl[4096];
    __shared__ int   sIdx[CAP];
    const int t  = threadIdx.x;
    const int r0 = blockIdx.x * 32;
    const int c4 = t & 31;
    const int sub = c4 >> 1;
    const int j0  = (c4 & 1) * 4;
    const int base = row_ptr[r0];
    const int bend = row_ptr[r0 + 32];

    for (int p = 0; p < 4; ++p) {
        const int nl   = p * 8 + (t >> 5);
        const int node = r0 + nl;
        const int lo = row_ptr[node], hi = row_ptr[node + 1];
        float4 aH = make_float4(0,0,0,0), aL = make_float4(0,0,0,0);
        float4 bH = make_float4(0,0,0,0), bL = make_float4(0,0,0,0);
        float4 cH = make_float4(0,0,0,0), cL = make_float4(0,0,0,0);
        float4 dH = make_float4(0,0,0,0), dL = make_float4(0,0,0,0);

        for (int cs = base; cs < bend; cs += CAP) {
            const int ce = (cs + CAP < bend) ? cs + CAP : bend;
            __syncthreads();                       // sIdx reuse guard
            for (int i = t; i < ce - cs; i += 256) sIdx[i] = esrc[cs + i];
            __syncthreads();
            int e  = (lo > cs) ? lo : cs;
            const int eh = (hi < ce) ? hi : ce;
            for (; e + 8 <= eh; e += 8) {
                const int rel = e - cs;
                int i0 = sIdx[rel+0], i1 = sIdx[rel+1], i2 = sIdx[rel+2], i3 = sIdx[rel+3];
                int i4 = sIdx[rel+4], i5 = sIdx[rel+5], i6 = sIdx[rel+6], i7 = sIdx[rel+7];
                uint4 u0 = *(const uint4*)(h + (size_t)i0 * HID + c4 * 4);
                uint4 u1 = *(const uint4*)(h + (size_t)i1 * HID + c4 * 4);
                uint4 u2 = *(const uint4*)(h + (size_t)i2 * HID + c4 * 4);
                uint4 u3 = *(const uint4*)(h + (size_t)i3 * HID + c4 * 4);
                uint4 u4 = *(const uint4*)(h + (size_t)i4 * HID + c4 * 4);
                uint4 u5 = *(const uint4*)(h + (size_t)i5 * HID + c4 * 4);
                uint4 u6 = *(const uint4*)(h + (size_t)i6 * HID + c4 * 4);
                uint4 u7 = *(const uint4*)(h + (size_t)i7 * HID + c4 * 4);
                ACCP(u0, aH, aL); ACCP(u1, bH, bL); ACCP(u2, cH, cL); ACCP(u3, dH, dL);
                ACCP(u4, aH, aL); ACCP(u5, bH, bL); ACCP(u6, cH, cL); ACCP(u7, dH, dL);
            }
            for (; e < eh; ++e) {
                int i0 = sIdx[e - cs];
                uint4 u0 = *(const uint4*)(h + (size_t)i0 * HID + c4 * 4);
                ACCP(u0, aH, aL);
            }
        }
        float vx = (aH.x + bH.x) + (cH.x + dH.x) + (aL.x + bL.x) + (cL.x + dL.x);
        float vy = (aH.y + bH.y) + (cH.y + dH.y) + (aL.y + bL.y) + (cL.y + dL.y);
        float vz = (aH.z + bH.z) + (cH.z + dH.z) + (aL.z + bL.z) + (cL.z + dL.z);
        float vw = (aH.w + bH.w) + (cH.w + dH.w) + (aL.w + bL.w) + (cL.w + dL.w);
        short4v Hq, Lq;
        short hh;
        hh = f2bf(vx); Hq.x = hh; Lq.x = f2bf(vx - bf2f(hh));
        hh = f2bf(vy); Hq.y = hh; Lq.y = f2bf(vy - bf2f(hh));
        hh = f2bf(vz); Hq.z = hh; Lq.z = f2bf(vz - bf2f(hh));
        hh = f2bf(vw); Hq.w = hh; Lq.w = f2bf(vw - bf2f(hh));
        const int off = sub * 256 + nl * 8 + j0;
        *(short4v*)(sAh + off) = Hq;
        *(short4v*)(sAl + off) = Lq;
    }
    __syncthreads();

    const int wv   = t >> 6;
    const int lane = t & 63;
    const int m31  = lane & 31;
    const int half = lane >> 5;
    floatx16 acc;
    #pragma unroll
    for (int i = 0; i < 16; ++i) acc[i] = 0.f;
    #pragma unroll
    for (int c = 0; c < 8; ++c) {
        short8 ah = *(const short8*)(sAh + (c * 2 + half) * 256 + m31 * 8);
        short8 al = *(const short8*)(sAl + (c * 2 + half) * 256 + m31 * 8);
        const uint* wr = Wq + ((size_t)(c * 4 + wv) * 64 + lane) * 8;
        uint4 w0 = *(const uint4*)(wr);
        uint4 w1 = *(const uint4*)(wr + 4);
        short8 bh, bl;
        unpack8(w0, w1, &bh, &bl);
        acc = __builtin_amdgcn_mfma_f32_32x32x16_bf16(ah, bh, acc, 0, 0, 0);
        acc = __builtin_amdgcn_mfma_f32_32x32x16_bf16(al, bh, acc, 0, 0, 0);
        acc = __builtin_amdgcn_mfma_f32_32x32x16_bf16(ah, bl, acc, 0, 0, 0);
    }
    const int col = wv * 32 + m31;
    const float bb = bias[col];
    #pragma unroll
    for (int reg = 0; reg < 16; ++reg) {
        int row = (reg & 3) + 8 * (reg >> 2) + 4 * half;
        float v = fmaxf(acc[reg] + bb, 0.f);
        out[(size_t)(r0 + row) * HID + col] = packsplit(v);
    }
}

// ---------------- standalone split-bf16 MFMA linear, 32-row tiles ----------
template<int PHASES, bool RELU>
__global__ __launch_bounds__(256, 4) void lin32_kernel(
    const uint* __restrict__ X0, const uint* __restrict__ X1,
    const uint* __restrict__ Wq, const float* __restrict__ bias,
    uint* __restrict__ out)
{
    __shared__ short sAh[PHASES * 4096];
    __shared__ short sAl[PHASES * 4096];
    const int t  = threadIdx.x;
    const int r0 = blockIdx.x * 32;

    #pragma unroll
    for (int i = 0; i < PHASES * 4; ++i) {
        int v = t + 256 * i;
        const uint* Xp = (PHASES == 2 && v >= 1024) ? X1 : X0;
        int vv  = v & 1023;
        int row = vv >> 5, q = vv & 31;
        uint4 u = *(const uint4*)(Xp + (size_t)(r0 + row) * 128 + q * 4);
        int kk  = ((PHASES == 2) ? (v >> 10) * 128 : 0) + q * 4;
        int off = (kk >> 3) * 256 + row * 8 + (q & 1) * 4;
        short4v hi, lo;
        hi.x = (short)(u.x >> 16); lo.x = (short)u.x;
        hi.y = (short)(u.y >> 16); lo.y = (short)u.y;
        hi.z = (short)(u.z >> 16); lo.z = (short)u.z;
        hi.w = (short)(u.w >> 16); lo.w = (short)u.w;
        *(short4v*)(sAh + off) = hi;
        *(short4v*)(sAl + off) = lo;
    }
    __syncthreads();

    const int wv   = t >> 6;
    const int lane = t & 63;
    const int m31  = lane & 31;
    const int half = lane >> 5;
    floatx16 acc;
    #pragma unroll
    for (int i = 0; i < 16; ++i) acc[i] = 0.f;
    #pragma unroll
    for (int c = 0; c < PHASES * 8; ++c) {
        short8 ah = *(const short8*)(sAh + (c * 2 + half) * 256 + m31 * 8);
        short8 al = *(const short8*)(sAl + (c * 2 + half) * 256 + m31 * 8);
        const uint* wr = Wq + ((size_t)(c * 4 + wv) * 64 + lane) * 8;
        uint4 w0 = *(const uint4*)(wr);
        uint4 w1 = *(const uint4*)(wr + 4);
        short8 bh, bl;
        unpack8(w0, w1, &bh, &bl);
        acc = __builtin_amdgcn_mfma_f32_32x32x16_bf16(ah, bh, acc, 0, 0, 0);
        acc = __builtin_amdgcn_mfma_f32_32x32x16_bf16(al, bh, acc, 0, 0, 0);
        acc = __builtin_amdgcn_mfma_f32_32x32x16_bf16(ah, bl, acc, 0, 0, 0);
    }
    const int col = wv * 32 + m31;
    const float bb = bias[col];
    #pragma unroll
    for (int reg = 0; reg < 16; ++reg) {
        int row = (reg & 3) + 8 * (reg >> 2) + 4 * half;
        float v = acc[reg] + bb;
        if (RELU) v = fmaxf(v, 0.f);
        out[(size_t)(r0 + row) * HID + col] = packsplit(v);
    }
}

// ---------------- cat-GEMM (Wb) + fused head ------------------------------
__global__ __launch_bounds__(256, 3) void cat_head_kernel(
    const uint* __restrict__ X0, const uint* __restrict__ X1,
    const uint* __restrict__ Wq, const float* __restrict__ bias,
    const float* __restrict__ f2, const float* __restrict__ f2b,
    float* __restrict__ out)
{
    __shared__ short sAh[8192];
    __shared__ short sAl[8192];
    __shared__ float gbuf[32 * 129];
    const int t  = threadIdx.x;
    const int r0 = blockIdx.x * 32;

    #pragma unroll
    for (int i = 0; i < 8; ++i) {
        int v = t + 256 * i;
        const uint* Xp = (v >= 1024) ? X1 : X0;
        int vv  = v & 1023;
        int row = vv >> 5, q = vv & 31;
        uint4 u = *(const uint4*)(Xp + (size_t)(r0 + row) * 128 + q * 4);
        int kk  = (v >> 10) * 128 + q * 4;
        int off = (kk >> 3) * 256 + row * 8 + (q & 1) * 4;
        short4v hi, lo;
        hi.x = (short)(u.x >> 16); lo.x = (short)u.x;
        hi.y = (short)(u.y >> 16); lo.y = (short)u.y;
        hi.z = (short)(u.z >> 16); lo.z = (short)u.z;
        hi.w = (short)(u.w >> 16); lo.w = (short)u.w;
        *(short4v*)(sAh + off) = hi;
        *(short4v*)(sAl + off) = lo;
    }
    __syncthreads();

    const int wv   = t >> 6;
    const int lane = t & 63;
    const int m31  = lane & 31;
    const int half = lane >> 5;
    floatx16 acc;
    #pragma unroll
    for (int i = 0; i < 16; ++i) acc[i] = 0.f;
    #pragma unroll
    for (int c = 0; c < 16; ++c) {
        short8 ah = *(const short8*)(sAh + (c * 2 + half) * 256 + m31 * 8);
        short8 al = *(const short8*)(sAl + (c * 2 + half) * 256 + m31 * 8);
        const uint* wr = Wq + ((size_t)(c * 4 + wv) * 64 + lane) * 8;
        uint4 w0 = *(const uint4*)(wr);
        uint4 w1 = *(const uint4*)(wr + 4);
        short8 bh, bl;
        unpack8(w0, w1, &bh, &bl);
        acc = __builtin_amdgcn_mfma_f32_32x32x16_bf16(ah, bh, acc, 0, 0, 0);
        acc = __builtin_amdgcn_mfma_f32_32x32x16_bf16(al, bh, acc, 0, 0, 0);
        acc = __builtin_amdgcn_mfma_f32_32x32x16_bf16(ah, bl, acc, 0, 0, 0);
    }
    const int col = wv * 32 + m31;
    const float bb = bias[col];
    #pragma unroll
    for (int reg = 0; reg < 16; ++reg) {
        int row = (reg & 3) + 8 * (reg >> 2) + 4 * half;
        gbuf[row * 129 + col] = fmaxf(acc[reg] + bb, 0.f);
    }
    __syncthreads();

    const int node = t >> 3;
    const int seg  = t & 7;
    const float* gr = gbuf + node * 129 + seg * 16;
    float a = 0.f;
    #pragma unroll
    for (int i = 0; i < 16; ++i) a += gr[i] * f2[seg * 16 + i];
    a += __shfl_down(a, 4, 8);
    a += __shfl_down(a, 2, 8);
    a += __shfl_down(a, 1, 8);
    if (seg == 0) out[r0 + node] = a + f2b[0];
}

// ---------------- fp32 linear for K=11 (first embed only), packs output ----
template<int K, bool RELU>
__global__ __launch_bounds__(128) void lin_kernel(
    const float* __restrict__ X, const float* __restrict__ W,
    const float* __restrict__ b, uint* __restrict__ out, int n_rows)
{
    constexpr int ROWS = 8;
    __shared__ float xs[ROWS * K];
    const int m  = threadIdx.x;
    const int r0 = blockIdx.x * ROWS;
    for (int i = threadIdx.x; i < ROWS * K; i += 128) {
        int r = i / K, k = i - r * K;
        int row = r0 + r;
        xs[i] = (row < n_rows) ? X[(size_t)row * K + k] : 0.f;
    }
    __syncthreads();
    float acc[ROWS] = {};
    const float* Wm = W + (size_t)m * K;
    for (int k = 0; k < K; ++k) {
        float w = Wm[k];
        #pragma unroll
        for (int r = 0; r < ROWS; ++r) acc[r] += xs[r * K + k] * w;
    }
    const float bias = b[m];
    #pragma unroll
    for (int r = 0; r < ROWS; ++r) {
        int row = r0 + r;
        if (row < n_rows) {
            float v = acc[r] + bias;
            if (RELU) v = fmaxf(v, 0.f);
            out[(size_t)row * HID + m] = packsplit(v);
        }
    }
}

// ---------------- weight prep: pack+swizzle c0_w2, c1_w2 -------------------
__global__ __launch_bounds__(256) void wprep_kernel(
    const float* __restrict__ w0, const float* __restrict__ w1,
    uint* __restrict__ wp)
{
    int i = blockIdx.x * 256 + threadIdx.x;
    if (i >= 32768) return;
    const float* src = (i < 16384) ? w0 : w1;
    int off = (i < 16384) ? 0 : 16384;
    int L = i - off;
    int o = L >> 7, k = L & 127;
    wp[off + wswz(o, k)] = packsplit(src[L]);
}

// ---------------- weight fold: Wq = swz(pack(A·B)), bias' = A·b_in + b_out --
__global__ __launch_bounds__(256) void wfold_kernel(
    const float* __restrict__ A, const float* __restrict__ B,
    const float* __restrict__ b_in, const float* __restrict__ b_out,
    uint* __restrict__ outWq, float* __restrict__ outBias)
{
    const int o = blockIdx.x;
    const int k = threadIdx.x;
    const float* Ar = A + o * 128;
    float s = 0.f;
    for (int j = 0; j < 128; ++j) s += Ar[j] * B[j * 256 + k];
    outWq[wswz(o, k)] = packsplit(s);
    if (k == 0) {
        float sb = 0.f;
        for (int j = 0; j < 128; ++j) sb += Ar[j] * b_in[j];
        outBias[o] = sb + b_out[o];
    }
}

// ---------------- CSR build (by dst) ----------------
__global__ __launch_bounds__(256) void hist_kernel(
    const int* __restrict__ dst, int* __restrict__ cnt)
{
    int e = blockIdx.x * 256 + threadIdx.x;
    if (e < NE) atomicAdd(&cnt[dst[e]], 1);
}

__global__ __launch_bounds__(256) void scan1_kernel(
    const int* __restrict__ cnt, int* __restrict__ row_ptr,
    int* __restrict__ partials)
{
    __shared__ int s[256];
    const int t = threadIdx.x;
    const int i = blockIdx.x * 256 + t;
    int v = (i < NN) ? cnt[i] : 0;
    s[t] = v;
    __syncthreads();
    #pragma unroll
    for (int off = 1; off < 256; off <<= 1) {
        int x = (t >= off) ? s[t - off] : 0;
        __syncthreads();
        s[t] += x;
        __syncthreads();
    }
    if (i < NN) row_ptr[i] = s[t] - v;
    if (t == 255) partials[blockIdx.x] = s[255];
}

__global__ __launch_bounds__(256) void scan2_kernel(
    int* __restrict__ partials, int* __restrict__ row_ptr)
{
    __shared__ int s[256];
    const int t = threadIdx.x;
    int v = (t < SCAN_BLK) ? partials[t] : 0;
    s[t] = v;
    __syncthreads();
    #pragma unroll
    for (int off = 1; off < 256; off <<= 1) {
        int x = (t >= off) ? s[t - off] : 0;
        __syncthreads();
        s[t] += x;
        __syncthreads();
    }
    if (t < SCAN_BLK) partials[t] = s[t] - v;
    if (t == 255) row_ptr[NN] = s[255];
}

__global__ __launch_bounds__(256) void scan3_kernel(
    int* __restrict__ row_ptr, const int* __restrict__ partials)
{
    const int i = blockIdx.x * 256 + threadIdx.x;
    if (i < NN) row_ptr[i] += partials[blockIdx.x];
}

__global__ __launch_bounds__(256) void fill_kernel(
    const int* __restrict__ src, const int* __restrict__ dst,
    const int* __restrict__ row_ptr, int* __restrict__ pos,
    int* __restrict__ esrc)
{
    int e = blockIdx.x * 256 + threadIdx.x;
    if (e >= NE) return;
    int d = dst[e];
    int p = row_ptr[d] + atomicAdd(&pos[d], 1);
    esrc[p] = src[e];
}

extern "C" void kernel_launch(void* const* d_in, const int* in_sizes, int n_in,
                              void* d_out, int out_size, void* d_ws, size_t ws_size,
                              hipStream_t stream)
{
    const float* x     = (const float*)d_in[0];
    const int*   eidx  = (const int*)d_in[1];
    const float* c0_w1 = (const float*)d_in[2],  *c0_b1 = (const float*)d_in[3];
    const float* c0_w2 = (const float*)d_in[4],  *c0_b2 = (const float*)d_in[5];
    const float* c0_w3 = (const float*)d_in[6],  *c0_b3 = (const float*)d_in[7];
    const float* c1_w1 = (const float*)d_in[8],  *c1_b1 = (const float*)d_in[9];
    const float* c1_w2 = (const float*)d_in[10], *c1_b2 = (const float*)d_in[11];
    const float* c1_w3 = (const float*)d_in[12], *c1_b3 = (const float*)d_in[13];
    const float* f_w1  = (const float*)d_in[14], *f_b1  = (const float*)d_in[15];
    const float* f_w2  = (const float*)d_in[16], *f_b2  = (const float*)d_in[17];
    const int* src = eidx;
    const int* dst = eidx + NE;
    float* out = (float*)d_out;

    const size_t BUF = (size_t)NN * HID;
    uint* bA = (uint*)d_ws;
    uint* bB = bA + BUF;
    uint* bC = bB + BUF;
    int* row_ptr  = (int*)(bC + BUF);        // NN+1
    int* cnt      = row_ptr + (NN + 1);      // NN (hist)
    int* pos      = cnt + NN;                // NN (fill cursor) — contiguous w/ cnt
    int* esrc     = pos + NN;                // NE
    int* partials = esrc + NE;               // SCAN_BLK
    uint* wp      = (uint*)(partials + SCAN_BLK);

    uint* p_c0w2 = wp + 0;          // 16384
    uint* p_c1w2 = wp + 16384;      // 16384
    uint* p_Wa   = wp + 32768;      // 32768 (c1_w1 · c0_w3)
    uint* p_Wb   = wp + 65536;      // 32768 (f_w1 · c1_w3)
    float* f_ba  = (float*)(wp + 98304);  // 128
    float* f_bb  = f_ba + 128;            // 128

    const int nb8 = (NN + 7) / 8;     // 5000 (K=11 embed)
    const int nbl = (NN + 31) / 32;   // 1250
    const int eb  = (NE + 255) / 256; // 2500

    // ---- weight prep (pack/swizzle + algebraic folds) + CSR build ----
    wprep_kernel<<<128, 256, 0, stream>>>(c0_w2, c1_w2, wp);
    wfold_kernel<<<128, 256, 0, stream>>>(c1_w1, c0_w3, c0_b3, c1_b1, p_Wa, f_ba);
    wfold_kernel<<<128, 256, 0, stream>>>(f_w1, c1_w3, c1_b3, f_b1, p_Wb, f_bb);
    (void)hipMemsetAsync(cnt, 0, 2 * NN * sizeof(int), stream);   // cnt + pos
    hist_kernel<<<eb, 256, 0, stream>>>(dst, cnt);
    scan1_kernel<<<SCAN_BLK, 256, 0, stream>>>(cnt, row_ptr, partials);
    scan2_kernel<<<1, 256, 0, stream>>>(partials, row_ptr);
    scan3_kernel<<<SCAN_BLK, 256, 0, stream>>>(row_ptr, partials);
    fill_kernel<<<eb, 256, 0, stream>>>(src, dst, row_ptr, pos, esrc);

    // ---- conv0 ----
    lin_kernel<11, true><<<nb8, 128, 0, stream>>>(x, c0_w1, c0_b1, bA, NN);       // h0
    fused_gather_lin_kernel<<<nbl, 256, 0, stream>>>(bA, row_ptr, esrc, p_c0w2, c0_b2, bB); // l1_0
    fused_gather_lin_kernel<<<nbl, 256, 0, stream>>>(bB, row_ptr, esrc, p_c0w2, c0_b2, bC); // l2_0
    lin32_kernel<2, true><<<nbl, 256, 0, stream>>>(bB, bC, p_Wa, f_ba, bA);       // h1 (folded)

    // ---- conv1 ----
    fused_gather_lin_kernel<<<nbl, 256, 0, stream>>>(bA, row_ptr, esrc, p_c1w2, c1_b2, bB); // l1_1
    fused_gather_lin_kernel<<<nbl, 256, 0, stream>>>(bB, row_ptr, esrc, p_c1w2, c1_b2, bC); // l2_1
    cat_head_kernel<<<nbl, 256, 0, stream>>>(bB, bC, p_Wb, f_bb, f_w2, f_b2, out); // folded tail
}

// Round 14
// 344.609 us; speedup vs baseline: 1.2985x; 1.2985x over previous
//
#include <hip/hip_runtime.h>
#include <hip/hip_fp16.h>

#define NN 40000
#define NE 640000
#define HID 128
#define SCAN_BLK ((NN + 255) / 256)   // 157

typedef __attribute__((ext_vector_type(8)))  short short8;
typedef __attribute__((ext_vector_type(4)))  short short4v;
typedef __attribute__((ext_vector_type(16))) float floatx16;
typedef unsigned int uint;

__device__ __forceinline__ short f2bf(float f) {
    union { float f; unsigned u; } c; c.f = f;
    unsigned u = c.u;
    unsigned r = (u + 0x7FFF + ((u >> 16) & 1)) >> 16;   // RNE
    return (short)r;
}
__device__ __forceinline__ float bf2f(short h) {
    union { unsigned u; float f; } c;
    c.u = ((unsigned)(unsigned short)h) << 16;
    return c.f;
}
__device__ __forceinline__ float2 h2f2(uint u) {
    union { uint u; __half2 h; } c; c.u = u;
    return __half22float2(c.h);
}
// fp16 storage rounding is the ONLY activation error; fp16 is exactly
// representable in the bf16 hi+lo split used for MFMA (11 bits <= ~17).
__device__ __forceinline__ void splits(float f, short* hi, short* lo) {
    short h = f2bf(f);
    *hi = h;
    *lo = f2bf(f - bf2f(h));
}
__device__ __forceinline__ void unpack8(uint4 a, uint4 b, short8* h, short8* l) {
    short8 H, L;
    H[0] = (short)(a.x >> 16); L[0] = (short)a.x;
    H[1] = (short)(a.y >> 16); L[1] = (short)a.y;
    H[2] = (short)(a.z >> 16); L[2] = (short)a.z;
    H[3] = (short)(a.w >> 16); L[3] = (short)a.w;
    H[4] = (short)(b.x >> 16); L[4] = (short)b.x;
    H[5] = (short)(b.y >> 16); L[5] = (short)b.y;
    H[6] = (short)(b.z >> 16); L[6] = (short)b.z;
    H[7] = (short)(b.w >> 16); L[7] = (short)b.w;
    *h = H; *l = L;
}

// W fragment swizzle (HW-verified r9-r13): element (o,k) of [128][WS] row-major
// -> index so a wave's B-load is base + lane*8 uints (coalesced).
__device__ __forceinline__ int wswz(int o, int k) {
    int chunk = k >> 4, half = (k >> 3) & 1, j = k & 7;
    int ct = o >> 5, m31 = o & 31;
    int lane = half * 32 + m31;
    return (((chunk * 4 + ct) * 64 + lane) * 8 + j);
}

#define ACCH(u, A)                                      \
    { float2 f0 = h2f2(u.x), f1 = h2f2(u.y);            \
      A.x += f0.x; A.y += f0.y; A.z += f1.x; A.w += f1.y; }

// ---------------- fused gather + split-bf16 MFMA linear (fp16 activations) --
// out[n][:] = fp16( relu( W · (sum_{e: dst=n} h[src[e]]) + b ) ), 32 nodes/blk.
// r11-proven loop: 4 passes x 8 nodes, unroll 4. Row = 256 B (32 x uint2).
__global__ __launch_bounds__(256, 4) void fused_gather_lin_kernel(
    const __half* __restrict__ h, const int* __restrict__ row_ptr,
    const int* __restrict__ esrc, const uint* __restrict__ Wq,
    const float* __restrict__ bias, __half* __restrict__ out)
{
    __shared__ short sAh[4096];
    __shared__ short sAl[4096];
    const int t  = threadIdx.x;
    const int r0 = blockIdx.x * 32;
    const int c4 = t & 31;               // elem group [4c4, 4c4+4)
    const int sub = c4 >> 1;
    const int j0  = (c4 & 1) * 4;
    const uint2* hp = (const uint2*)h;   // row = 32 uint2

    for (int p = 0; p < 4; ++p) {
        const int nl   = p * 8 + (t >> 5);
        const int node = r0 + nl;
        const int lo = row_ptr[node], hi = row_ptr[node + 1];
        float4 a = make_float4(0,0,0,0), b = make_float4(0,0,0,0);
        float4 c = make_float4(0,0,0,0), d = make_float4(0,0,0,0);
        int e = lo;
        for (; e + 4 <= hi; e += 4) {
            int s0 = esrc[e], s1 = esrc[e+1], s2 = esrc[e+2], s3 = esrc[e+3];
            uint2 u0 = hp[(size_t)s0 * 32 + c4];
            uint2 u1 = hp[(size_t)s1 * 32 + c4];
            uint2 u2 = hp[(size_t)s2 * 32 + c4];
            uint2 u3 = hp[(size_t)s3 * 32 + c4];
            ACCH(u0, a); ACCH(u1, b); ACCH(u2, c); ACCH(u3, d);
        }
        for (; e < hi; ++e) {
            int s0 = esrc[e];
            uint2 u0 = hp[(size_t)s0 * 32 + c4];
            ACCH(u0, a);
        }
        float vx = (a.x + b.x) + (c.x + d.x);
        float vy = (a.y + b.y) + (c.y + d.y);
        float vz = (a.z + b.z) + (c.z + d.z);
        float vw = (a.w + b.w) + (c.w + d.w);
        short4v Hq, Lq;
        short hh, ll;
        splits(vx, &hh, &ll); Hq.x = hh; Lq.x = ll;
        splits(vy, &hh, &ll); Hq.y = hh; Lq.y = ll;
        splits(vz, &hh, &ll); Hq.z = hh; Lq.z = ll;
        splits(vw, &hh, &ll); Hq.w = hh; Lq.w = ll;
        const int off = sub * 256 + nl * 8 + j0;
        *(short4v*)(sAh + off) = Hq;
        *(short4v*)(sAl + off) = Lq;
    }
    __syncthreads();

    const int wv   = t >> 6;
    const int lane = t & 63;
    const int m31  = lane & 31;
    const int half = lane >> 5;
    floatx16 acc;
    #pragma unroll
    for (int i = 0; i < 16; ++i) acc[i] = 0.f;
    #pragma unroll
    for (int c = 0; c < 8; ++c) {
        short8 ah = *(const short8*)(sAh + (c * 2 + half) * 256 + m31 * 8);
        short8 al = *(const short8*)(sAl + (c * 2 + half) * 256 + m31 * 8);
        const uint* wr = Wq + ((size_t)(c * 4 + wv) * 64 + lane) * 8;
        uint4 w0 = *(const uint4*)(wr);
        uint4 w1 = *(const uint4*)(wr + 4);
        short8 bh, bl;
        unpack8(w0, w1, &bh, &bl);
        acc = __builtin_amdgcn_mfma_f32_32x32x16_bf16(ah, bh, acc, 0, 0, 0);
        acc = __builtin_amdgcn_mfma_f32_32x32x16_bf16(al, bh, acc, 0, 0, 0);
        acc = __builtin_amdgcn_mfma_f32_32x32x16_bf16(ah, bl, acc, 0, 0, 0);
    }
    const int col = wv * 32 + m31;
    const float bb = bias[col];
    #pragma unroll
    for (int reg = 0; reg < 16; ++reg) {
        int row = (reg & 3) + 8 * (reg >> 2) + 4 * half;
        float v = fmaxf(acc[reg] + bb, 0.f);
        out[(size_t)(r0 + row) * HID + col] = __float2half(v);
    }
}

// ---------------- standalone split-bf16 MFMA linear, 32-row tiles -----------
template<int PHASES, bool RELU>
__global__ __launch_bounds__(256, 4) void lin32_kernel(
    const __half* __restrict__ X0, const __half* __restrict__ X1,
    const uint* __restrict__ Wq, const float* __restrict__ bias,
    __half* __restrict__ out)
{
    __shared__ short sAh[PHASES * 4096];
    __shared__ short sAl[PHASES * 4096];
    const int t  = threadIdx.x;
    const int r0 = blockIdx.x * 32;

    #pragma unroll
    for (int i = 0; i < PHASES * 4; ++i) {
        int v = t + 256 * i;
        const __half* Xp = (PHASES == 2 && v >= 1024) ? X1 : X0;
        int vv  = v & 1023;
        int row = vv >> 5, q = vv & 31;
        uint2 u = *(const uint2*)(Xp + (size_t)(r0 + row) * 128 + q * 4);
        float2 f0 = h2f2(u.x), f1 = h2f2(u.y);
        int kk  = ((PHASES == 2) ? (v >> 10) * 128 : 0) + q * 4;
        int off = (kk >> 3) * 256 + row * 8 + (q & 1) * 4;
        short4v hi, lo;
        short hh, ll;
        splits(f0.x, &hh, &ll); hi.x = hh; lo.x = ll;
        splits(f0.y, &hh, &ll); hi.y = hh; lo.y = ll;
        splits(f1.x, &hh, &ll); hi.z = hh; lo.z = ll;
        splits(f1.y, &hh, &ll); hi.w = hh; lo.w = ll;
        *(short4v*)(sAh + off) = hi;
        *(short4v*)(sAl + off) = lo;
    }
    __syncthreads();

    const int wv   = t >> 6;
    const int lane = t & 63;
    const int m31  = lane & 31;
    const int half = lane >> 5;
    floatx16 acc;
    #pragma unroll
    for (int i = 0; i < 16; ++i) acc[i] = 0.f;
    #pragma unroll
    for (int c = 0; c < PHASES * 8; ++c) {
        short8 ah = *(const short8*)(sAh + (c * 2 + half) * 256 + m31 * 8);
        short8 al = *(const short8*)(sAl + (c * 2 + half) * 256 + m31 * 8);
        const uint* wr = Wq + ((size_t)(c * 4 + wv) * 64 + lane) * 8;
        uint4 w0 = *(const uint4*)(wr);
        uint4 w1 = *(const uint4*)(wr + 4);
        short8 bh, bl;
        unpack8(w0, w1, &bh, &bl);
        acc = __builtin_amdgcn_mfma_f32_32x32x16_bf16(ah, bh, acc, 0, 0, 0);
        acc = __builtin_amdgcn_mfma_f32_32x32x16_bf16(al, bh, acc, 0, 0, 0);
        acc = __builtin_amdgcn_mfma_f32_32x32x16_bf16(ah, bl, acc, 0, 0, 0);
    }
    const int col = wv * 32 + m31;
    const float bb = bias[col];
    #pragma unroll
    for (int reg = 0; reg < 16; ++reg) {
        int row = (reg & 3) + 8 * (reg >> 2) + 4 * half;
        float v = acc[reg] + bb;
        if (RELU) v = fmaxf(v, 0.f);
        out[(size_t)(r0 + row) * HID + col] = __float2half(v);
    }
}

// ---------------- cat-GEMM (Wb) + fused head --------------------------------
__global__ __launch_bounds__(256, 3) void cat_head_kernel(
    const __half* __restrict__ X0, const __half* __restrict__ X1,
    const uint* __restrict__ Wq, const float* __restrict__ bias,
    const float* __restrict__ f2, const float* __restrict__ f2b,
    float* __restrict__ out)
{
    __shared__ short sAh[8192];
    __shared__ short sAl[8192];
    __shared__ float gbuf[32 * 129];
    const int t  = threadIdx.x;
    const int r0 = blockIdx.x * 32;

    #pragma unroll
    for (int i = 0; i < 8; ++i) {
        int v = t + 256 * i;
        const __half* Xp = (v >= 1024) ? X1 : X0;
        int vv  = v & 1023;
        int row = vv >> 5, q = vv & 31;
        uint2 u = *(const uint2*)(Xp + (size_t)(r0 + row) * 128 + q * 4);
        float2 f0 = h2f2(u.x), f1 = h2f2(u.y);
        int kk  = (v >> 10) * 128 + q * 4;
        int off = (kk >> 3) * 256 + row * 8 + (q & 1) * 4;
        short4v hi, lo;
        short hh, ll;
        splits(f0.x, &hh, &ll); hi.x = hh; lo.x = ll;
        splits(f0.y, &hh, &ll); hi.y = hh; lo.y = ll;
        splits(f1.x, &hh, &ll); hi.z = hh; lo.z = ll;
        splits(f1.y, &hh, &ll); hi.w = hh; lo.w = ll;
        *(short4v*)(sAh + off) = hi;
        *(short4v*)(sAl + off) = lo;
    }
    __syncthreads();

    const int wv   = t >> 6;
    const int lane = t & 63;
    const int m31  = lane & 31;
    const int half = lane >> 5;
    floatx16 acc;
    #pragma unroll
    for (int i = 0; i < 16; ++i) acc[i] = 0.f;
    #pragma unroll
    for (int c = 0; c < 16; ++c) {
        short8 ah = *(const short8*)(sAh + (c * 2 + half) * 256 + m31 * 8);
        short8 al = *(const short8*)(sAl + (c * 2 + half) * 256 + m31 * 8);
        const uint* wr = Wq + ((size_t)(c * 4 + wv) * 64 + lane) * 8;
        uint4 w0 = *(const uint4*)(wr);
        uint4 w1 = *(const uint4*)(wr + 4);
        short8 bh, bl;
        unpack8(w0, w1, &bh, &bl);
        acc = __builtin_amdgcn_mfma_f32_32x32x16_bf16(ah, bh, acc, 0, 0, 0);
        acc = __builtin_amdgcn_mfma_f32_32x32x16_bf16(al, bh, acc, 0, 0, 0);
        acc = __builtin_amdgcn_mfma_f32_32x32x16_bf16(ah, bl, acc, 0, 0, 0);
    }
    const int col = wv * 32 + m31;
    const float bb = bias[col];
    #pragma unroll
    for (int reg = 0; reg < 16; ++reg) {
        int row = (reg & 3) + 8 * (reg >> 2) + 4 * half;
        gbuf[row * 129 + col] = fmaxf(acc[reg] + bb, 0.f);
    }
    __syncthreads();

    const int node = t >> 3;
    const int seg  = t & 7;
    const float* gr = gbuf + node * 129 + seg * 16;
    float a = 0.f;
    #pragma unroll
    for (int i = 0; i < 16; ++i) a += gr[i] * f2[seg * 16 + i];
    a += __shfl_down(a, 4, 8);
    a += __shfl_down(a, 2, 8);
    a += __shfl_down(a, 1, 8);
    if (seg == 0) out[r0 + node] = a + f2b[0];
}

// ---------------- fp32 linear for K=11 (first embed only), fp16 output ------
template<int K, bool RELU>
__global__ __launch_bounds__(128) void lin_kernel(
    const float* __restrict__ X, const float* __restrict__ W,
    const float* __restrict__ b, __half* __restrict__ out, int n_rows)
{
    constexpr int ROWS = 8;
    __shared__ float xs[ROWS * K];
    const int m  = threadIdx.x;
    const int r0 = blockIdx.x * ROWS;
    for (int i = threadIdx.x; i < ROWS * K; i += 128) {
        int r = i / K, k = i - r * K;
        int row = r0 + r;
        xs[i] = (row < n_rows) ? X[(size_t)row * K + k] : 0.f;
    }
    __syncthreads();
    float acc[ROWS] = {};
    const float* Wm = W + (size_t)m * K;
    for (int k = 0; k < K; ++k) {
        float w = Wm[k];
        #pragma unroll
        for (int r = 0; r < ROWS; ++r) acc[r] += xs[r * K + k] * w;
    }
    const float bias = b[m];
    #pragma unroll
    for (int r = 0; r < ROWS; ++r) {
        int row = r0 + r;
        if (row < n_rows) {
            float v = acc[r] + bias;
            if (RELU) v = fmaxf(v, 0.f);
            out[(size_t)row * HID + m] = __float2half(v);
        }
    }
}

// ---------------- weight prep: pack+swizzle c0_w2, c1_w2 --------------------
__global__ __launch_bounds__(256) void wprep_kernel(
    const float* __restrict__ w0, const float* __restrict__ w1,
    uint* __restrict__ wp)
{
    int i = blockIdx.x * 256 + threadIdx.x;
    if (i >= 32768) return;
    const float* src = (i < 16384) ? w0 : w1;
    int off = (i < 16384) ? 0 : 16384;
    int L = i - off;
    int o = L >> 7, k = L & 127;
    float f = src[L];
    short hh, ll;
    splits(f, &hh, &ll);
    wp[off + wswz(o, k)] = ((uint)(unsigned short)hh << 16) | (uint)(unsigned short)ll;
}

// ---------------- weight fold: Wq = swz(pack(A·B)), bias' = A·b_in + b_out --
__global__ __launch_bounds__(256) void wfold_kernel(
    const float* __restrict__ A, const float* __restrict__ B,
    const float* __restrict__ b_in, const float* __restrict__ b_out,
    uint* __restrict__ outWq, float* __restrict__ outBias)
{
    const int o = blockIdx.x;
    const int k = threadIdx.x;
    const float* Ar = A + o * 128;
    float s = 0.f;
    for (int j = 0; j < 128; ++j) s += Ar[j] * B[j * 256 + k];
    short hh, ll;
    splits(s, &hh, &ll);
    outWq[wswz(o, k)] = ((uint)(unsigned short)hh << 16) | (uint)(unsigned short)ll;
    if (k == 0) {
        float sb = 0.f;
        for (int j = 0; j < 128; ++j) sb += Ar[j] * b_in[j];
        outBias[o] = sb + b_out[o];
    }
}

// ---------------- CSR build (by dst) ----------------
__global__ __launch_bounds__(256) void hist_kernel(
    const int* __restrict__ dst, int* __restrict__ cnt)
{
    int e = blockIdx.x * 256 + threadIdx.x;
    if (e < NE) atomicAdd(&cnt[dst[e]], 1);
}

__global__ __launch_bounds__(256) void scan1_kernel(
    const int* __restrict__ cnt, int* __restrict__ row_ptr,
    int* __restrict__ partials)
{
    __shared__ int s[256];
    const int t = threadIdx.x;
    const int i = blockIdx.x * 256 + t;
    int v = (i < NN) ? cnt[i] : 0;
    s[t] = v;
    __syncthreads();
    #pragma unroll
    for (int off = 1; off < 256; off <<= 1) {
        int x = (t >= off) ? s[t - off] : 0;
        __syncthreads();
        s[t] += x;
        __syncthreads();
    }
    if (i < NN) row_ptr[i] = s[t] - v;
    if (t == 255) partials[blockIdx.x] = s[255];
}

__global__ __launch_bounds__(256) void scan2_kernel(
    int* __restrict__ partials, int* __restrict__ row_ptr)
{
    __shared__ int s[256];
    const int t = threadIdx.x;
    int v = (t < SCAN_BLK) ? partials[t] : 0;
    s[t] = v;
    __syncthreads();
    #pragma unroll
    for (int off = 1; off < 256; off <<= 1) {
        int x = (t >= off) ? s[t - off] : 0;
        __syncthreads();
        s[t] += x;
        __syncthreads();
    }
    if (t < SCAN_BLK) partials[t] = s[t] - v;
    if (t == 255) row_ptr[NN] = s[255];
}

__global__ __launch_bounds__(256) void scan3_kernel(
    int* __restrict__ row_ptr, const int* __restrict__ partials)
{
    const int i = blockIdx.x * 256 + threadIdx.x;
    if (i < NN) row_ptr[i] += partials[blockIdx.x];
}

__global__ __launch_bounds__(256) void fill_kernel(
    const int* __restrict__ src, const int* __restrict__ dst,
    const int* __restrict__ row_ptr, int* __restrict__ pos,
    int* __restrict__ esrc)
{
    int e = blockIdx.x * 256 + threadIdx.x;
    if (e >= NE) return;
    int d = dst[e];
    int p = row_ptr[d] + atomicAdd(&pos[d], 1);
    esrc[p] = src[e];
}

extern "C" void kernel_launch(void* const* d_in, const int* in_sizes, int n_in,
                              void* d_out, int out_size, void* d_ws, size_t ws_size,
                              hipStream_t stream)
{
    const float* x     = (const float*)d_in[0];
    const int*   eidx  = (const int*)d_in[1];
    const float* c0_w1 = (const float*)d_in[2],  *c0_b1 = (const float*)d_in[3];
    const float* c0_w2 = (const float*)d_in[4],  *c0_b2 = (const float*)d_in[5];
    const float* c0_w3 = (const float*)d_in[6],  *c0_b3 = (const float*)d_in[7];
    const float* c1_w1 = (const float*)d_in[8],  *c1_b1 = (const float*)d_in[9];
    const float* c1_w2 = (const float*)d_in[10], *c1_b2 = (const float*)d_in[11];
    const float* c1_w3 = (const float*)d_in[12], *c1_b3 = (const float*)d_in[13];
    const float* f_w1  = (const float*)d_in[14], *f_b1  = (const float*)d_in[15];
    const float* f_w2  = (const float*)d_in[16], *f_b2  = (const float*)d_in[17];
    const int* src = eidx;
    const int* dst = eidx + NE;
    float* out = (float*)d_out;

    const size_t BUF = (size_t)NN * HID;          // elems per activation buffer
    __half* bA = (__half*)d_ws;
    __half* bB = bA + BUF;
    __half* bC = bB + BUF;
    int* row_ptr  = (int*)(bC + BUF);        // NN+1 (half*3 = 30.7 MB, 4B-aligned)
    int* cnt      = row_ptr + (NN + 1);      // NN (hist)
    int* pos      = cnt + NN;                // NN (fill cursor)
    int* esrc     = pos + NN;                // NE
    int* partials = esrc + NE;               // SCAN_BLK
    uint* wp      = (uint*)(partials + SCAN_BLK);

    uint* p_c0w2 = wp + 0;          // 16384
    uint* p_c1w2 = wp + 16384;      // 16384
    uint* p_Wa   = wp + 32768;      // 32768 (c1_w1 · c0_w3)
    uint* p_Wb   = wp + 65536;      // 32768 (f_w1 · c1_w3)
    float* f_ba  = (float*)(wp + 98304);  // 128
    float* f_bb  = f_ba + 128;            // 128

    const int nb8 = (NN + 7) / 8;     // 5000 (K=11 embed)
    const int nbl = (NN + 31) / 32;   // 1250
    const int eb  = (NE + 255) / 256; // 2500

    // ---- weight prep (pack/swizzle + algebraic folds) + CSR build ----
    wprep_kernel<<<128, 256, 0, stream>>>(c0_w2, c1_w2, wp);
    wfold_kernel<<<128, 256, 0, stream>>>(c1_w1, c0_w3, c0_b3, c1_b1, p_Wa, f_ba);
    wfold_kernel<<<128, 256, 0, stream>>>(f_w1, c1_w3, c1_b3, f_b1, p_Wb, f_bb);
    (void)hipMemsetAsync(cnt, 0, 2 * NN * sizeof(int), stream);   // cnt + pos
    hist_kernel<<<eb, 256, 0, stream>>>(dst, cnt);
    scan1_kernel<<<SCAN_BLK, 256, 0, stream>>>(cnt, row_ptr, partials);
    scan2_kernel<<<1, 256, 0, stream>>>(partials, row_ptr);
    scan3_kernel<<<SCAN_BLK, 256, 0, stream>>>(row_ptr, partials);
    fill_kernel<<<eb, 256, 0, stream>>>(src, dst, row_ptr, pos, esrc);

    // ---- conv0 ----
    lin_kernel<11, true><<<nb8, 128, 0, stream>>>(x, c0_w1, c0_b1, bA, NN);       // h0
    fused_gather_lin_kernel<<<nbl, 256, 0, stream>>>(bA, row_ptr, esrc, p_c0w2, c0_b2, bB); // l1_0
    fused_gather_lin_kernel<<<nbl, 256, 0, stream>>>(bB, row_ptr, esrc, p_c0w2, c0_b2, bC); // l2_0
    lin32_kernel<2, true><<<nbl, 256, 0, stream>>>(bB, bC, p_Wa, f_ba, bA);       // h1 (folded)

    // ---- conv1 ----
    fused_gather_lin_kernel<<<nbl, 256, 0, stream>>>(bA, row_ptr, esrc, p_c1w2, c1_b2, bB); // l1_1
    fused_gather_lin_kernel<<<nbl, 256, 0, stream>>>(bB, row_ptr, esrc, p_c1w2, c1_b2, bC); // l2_1
    cat_head_kernel<<<nbl, 256, 0, stream>>>(bB, bC, p_Wb, f_bb, f_w2, f_b2, out); // folded tail
}

// Round 15
// 331.081 us; speedup vs baseline: 1.3516x; 1.0409x over previous
//
#include <hip/hip_runtime.h>
#include <hip/hip_fp16.h>

#define NN 40000
#define NE 640000
#define HID 128
#define SCAN_BLK ((NN + 255) / 256)   // 157
#define EB ((NE + 255) / 256)         // 2500

typedef __attribute__((ext_vector_type(8)))  short short8;
typedef __attribute__((ext_vector_type(4)))  short short4v;
typedef __attribute__((ext_vector_type(16))) float floatx16;
typedef unsigned int uint;

__device__ __forceinline__ short f2bf(float f) {
    union { float f; unsigned u; } c; c.f = f;
    unsigned u = c.u;
    unsigned r = (u + 0x7FFF + ((u >> 16) & 1)) >> 16;   // RNE
    return (short)r;
}
__device__ __forceinline__ float bf2f(short h) {
    union { unsigned u; float f; } c;
    c.u = ((unsigned)(unsigned short)h) << 16;
    return c.f;
}
__device__ __forceinline__ float2 h2f2(uint u) {
    union { uint u; __half2 h; } c; c.u = u;
    return __half22float2(c.h);
}
__device__ __forceinline__ void splits(float f, short* hi, short* lo) {
    short h = f2bf(f);
    *hi = h;
    *lo = f2bf(f - bf2f(h));
}
__device__ __forceinline__ void unpack8(uint4 a, uint4 b, short8* h, short8* l) {
    short8 H, L;
    H[0] = (short)(a.x >> 16); L[0] = (short)a.x;
    H[1] = (short)(a.y >> 16); L[1] = (short)a.y;
    H[2] = (short)(a.z >> 16); L[2] = (short)a.z;
    H[3] = (short)(a.w >> 16); L[3] = (short)a.w;
    H[4] = (short)(b.x >> 16); L[4] = (short)b.x;
    H[5] = (short)(b.y >> 16); L[5] = (short)b.y;
    H[6] = (short)(b.z >> 16); L[6] = (short)b.z;
    H[7] = (short)(b.w >> 16); L[7] = (short)b.w;
    *h = H; *l = L;
}

// W fragment swizzle (HW-verified r9-r14)
__device__ __forceinline__ int wswz(int o, int k) {
    int chunk = k >> 4, half = (k >> 3) & 1, j = k & 7;
    int ct = o >> 5, m31 = o & 31;
    int lane = half * 32 + m31;
    return (((chunk * 4 + ct) * 64 + lane) * 8 + j);
}

#define ACCH(u, A)                                      \
    { float2 f0 = h2f2(u.x), f1 = h2f2(u.y);            \
      A.x += f0.x; A.y += f0.y; A.z += f1.x; A.w += f1.y; }

// ---------------- fused gather + split-bf16 MFMA linear (fp16 activations) --
// out[n][:] = fp16( relu( W · (sum_{e: dst=n} h[src[e]]) + b ) ), 32 nodes/blk.
// Gather: 8 lane-groups steal nodes from an LDS counter (degree balance);
// per-node arithmetic order unchanged -> bit-identical to static schedule.
__global__ __launch_bounds__(256, 4) void fused_gather_lin_kernel(
    const __half* __restrict__ h, const int* __restrict__ row_ptr,
    const int* __restrict__ esrc, const uint* __restrict__ Wq,
    const float* __restrict__ bias, __half* __restrict__ out)
{
    __shared__ short sAh[4096];
    __shared__ short sAl[4096];
    __shared__ int   sCtr;
    const int t  = threadIdx.x;
    const int r0 = blockIdx.x * 32;
    const int c4 = t & 31;
    const int sub = c4 >> 1;
    const int j0  = (c4 & 1) * 4;
    const uint2* hp = (const uint2*)h;   // row = 32 uint2

    if (t == 0) sCtr = 0;
    __syncthreads();

    for (;;) {
        int n = 0;
        if ((t & 31) == 0) n = atomicAdd(&sCtr, 1);
        n = __shfl(n, 0, 32);
        if (n >= 32) break;
        const int node = r0 + n;
        const int lo = row_ptr[node], hi = row_ptr[node + 1];
        float4 a = make_float4(0,0,0,0), b = make_float4(0,0,0,0);
        float4 c = make_float4(0,0,0,0), d = make_float4(0,0,0,0);
        int e = lo;
        for (; e + 4 <= hi; e += 4) {
            int s0 = esrc[e], s1 = esrc[e+1], s2 = esrc[e+2], s3 = esrc[e+3];
            uint2 u0 = hp[(size_t)s0 * 32 + c4];
            uint2 u1 = hp[(size_t)s1 * 32 + c4];
            uint2 u2 = hp[(size_t)s2 * 32 + c4];
            uint2 u3 = hp[(size_t)s3 * 32 + c4];
            ACCH(u0, a); ACCH(u1, b); ACCH(u2, c); ACCH(u3, d);
        }
        for (; e < hi; ++e) {
            int s0 = esrc[e];
            uint2 u0 = hp[(size_t)s0 * 32 + c4];
            ACCH(u0, a);
        }
        float vx = (a.x + b.x) + (c.x + d.x);
        float vy = (a.y + b.y) + (c.y + d.y);
        float vz = (a.z + b.z) + (c.z + d.z);
        float vw = (a.w + b.w) + (c.w + d.w);
        short4v Hq, Lq;
        short hh, ll;
        splits(vx, &hh, &ll); Hq.x = hh; Lq.x = ll;
        splits(vy, &hh, &ll); Hq.y = hh; Lq.y = ll;
        splits(vz, &hh, &ll); Hq.z = hh; Lq.z = ll;
        splits(vw, &hh, &ll); Hq.w = hh; Lq.w = ll;
        const int off = sub * 256 + n * 8 + j0;
        *(short4v*)(sAh + off) = Hq;
        *(short4v*)(sAl + off) = Lq;
    }
    __syncthreads();

    const int wv   = t >> 6;
    const int lane = t & 63;
    const int m31  = lane & 31;
    const int half = lane >> 5;
    floatx16 acc;
    #pragma unroll
    for (int i = 0; i < 16; ++i) acc[i] = 0.f;
    #pragma unroll
    for (int c = 0; c < 8; ++c) {
        short8 ah = *(const short8*)(sAh + (c * 2 + half) * 256 + m31 * 8);
        short8 al = *(const short8*)(sAl + (c * 2 + half) * 256 + m31 * 8);
        const uint* wr = Wq + ((size_t)(c * 4 + wv) * 64 + lane) * 8;
        uint4 w0 = *(const uint4*)(wr);
        uint4 w1 = *(const uint4*)(wr + 4);
        short8 bh, bl;
        unpack8(w0, w1, &bh, &bl);
        acc = __builtin_amdgcn_mfma_f32_32x32x16_bf16(ah, bh, acc, 0, 0, 0);
        acc = __builtin_amdgcn_mfma_f32_32x32x16_bf16(al, bh, acc, 0, 0, 0);
        acc = __builtin_amdgcn_mfma_f32_32x32x16_bf16(ah, bl, acc, 0, 0, 0);
    }
    const int col = wv * 32 + m31;
    const float bb = bias[col];
    #pragma unroll
    for (int reg = 0; reg < 16; ++reg) {
        int row = (reg & 3) + 8 * (reg >> 2) + 4 * half;
        float v = fmaxf(acc[reg] + bb, 0.f);
        out[(size_t)(r0 + row) * HID + col] = __float2half(v);
    }
}

// ---------------- standalone split-bf16 MFMA linear, 32-row tiles -----------
template<int PHASES, bool RELU>
__global__ __launch_bounds__(256, 4) void lin32_kernel(
    const __half* __restrict__ X0, const __half* __restrict__ X1,
    const uint* __restrict__ Wq, const float* __restrict__ bias,
    __half* __restrict__ out)
{
    __shared__ short sAh[PHASES * 4096];
    __shared__ short sAl[PHASES * 4096];
    const int t  = threadIdx.x;
    const int r0 = blockIdx.x * 32;

    #pragma unroll
    for (int i = 0; i < PHASES * 4; ++i) {
        int v = t + 256 * i;
        const __half* Xp = (PHASES == 2 && v >= 1024) ? X1 : X0;
        int vv  = v & 1023;
        int row = vv >> 5, q = vv & 31;
        uint2 u = *(const uint2*)(Xp + (size_t)(r0 + row) * 128 + q * 4);
        float2 f0 = h2f2(u.x), f1 = h2f2(u.y);
        int kk  = ((PHASES == 2) ? (v >> 10) * 128 : 0) + q * 4;
        int off = (kk >> 3) * 256 + row * 8 + (q & 1) * 4;
        short4v hi, lo;
        short hh, ll;
        splits(f0.x, &hh, &ll); hi.x = hh; lo.x = ll;
        splits(f0.y, &hh, &ll); hi.y = hh; lo.y = ll;
        splits(f1.x, &hh, &ll); hi.z = hh; lo.z = ll;
        splits(f1.y, &hh, &ll); hi.w = hh; lo.w = ll;
        *(short4v*)(sAh + off) = hi;
        *(short4v*)(sAl + off) = lo;
    }
    __syncthreads();

    const int wv   = t >> 6;
    const int lane = t & 63;
    const int m31  = lane & 31;
    const int half = lane >> 5;
    floatx16 acc;
    #pragma unroll
    for (int i = 0; i < 16; ++i) acc[i] = 0.f;
    #pragma unroll
    for (int c = 0; c < PHASES * 8; ++c) {
        short8 ah = *(const short8*)(sAh + (c * 2 + half) * 256 + m31 * 8);
        short8 al = *(const short8*)(sAl + (c * 2 + half) * 256 + m31 * 8);
        const uint* wr = Wq + ((size_t)(c * 4 + wv) * 64 + lane) * 8;
        uint4 w0 = *(const uint4*)(wr);
        uint4 w1 = *(const uint4*)(wr + 4);
        short8 bh, bl;
        unpack8(w0, w1, &bh, &bl);
        acc = __builtin_amdgcn_mfma_f32_32x32x16_bf16(ah, bh, acc, 0, 0, 0);
        acc = __builtin_amdgcn_mfma_f32_32x32x16_bf16(al, bh, acc, 0, 0, 0);
        acc = __builtin_amdgcn_mfma_f32_32x32x16_bf16(ah, bl, acc, 0, 0, 0);
    }
    const int col = wv * 32 + m31;
    const float bb = bias[col];
    #pragma unroll
    for (int reg = 0; reg < 16; ++reg) {
        int row = (reg & 3) + 8 * (reg >> 2) + 4 * half;
        float v = acc[reg] + bb;
        if (RELU) v = fmaxf(v, 0.f);
        out[(size_t)(r0 + row) * HID + col] = __float2half(v);
    }
}

// ---------------- cat-GEMM (Wb) + fused head --------------------------------
__global__ __launch_bounds__(256, 3) void cat_head_kernel(
    const __half* __restrict__ X0, const __half* __restrict__ X1,
    const uint* __restrict__ Wq, const float* __restrict__ bias,
    const float* __restrict__ f2, const float* __restrict__ f2b,
    float* __restrict__ out)
{
    __shared__ short sAh[8192];
    __shared__ short sAl[8192];
    __shared__ float gbuf[32 * 129];
    const int t  = threadIdx.x;
    const int r0 = blockIdx.x * 32;

    #pragma unroll
    for (int i = 0; i < 8; ++i) {
        int v = t + 256 * i;
        const __half* Xp = (v >= 1024) ? X1 : X0;
        int vv  = v & 1023;
        int row = vv >> 5, q = vv & 31;
        uint2 u = *(const uint2*)(Xp + (size_t)(r0 + row) * 128 + q * 4);
        float2 f0 = h2f2(u.x), f1 = h2f2(u.y);
        int kk  = (v >> 10) * 128 + q * 4;
        int off = (kk >> 3) * 256 + row * 8 + (q & 1) * 4;
        short4v hi, lo;
        short hh, ll;
        splits(f0.x, &hh, &ll); hi.x = hh; lo.x = ll;
        splits(f0.y, &hh, &ll); hi.y = hh; lo.y = ll;
        splits(f1.x, &hh, &ll); hi.z = hh; lo.z = ll;
        splits(f1.y, &hh, &ll); hi.w = hh; lo.w = ll;
        *(short4v*)(sAh + off) = hi;
        *(short4v*)(sAl + off) = lo;
    }
    __syncthreads();

    const int wv   = t >> 6;
    const int lane = t & 63;
    const int m31  = lane & 31;
    const int half = lane >> 5;
    floatx16 acc;
    #pragma unroll
    for (int i = 0; i < 16; ++i) acc[i] = 0.f;
    #pragma unroll
    for (int c = 0; c < 16; ++c) {
        short8 ah = *(const short8*)(sAh + (c * 2 + half) * 256 + m31 * 8);
        short8 al = *(const short8*)(sAl + (c * 2 + half) * 256 + m31 * 8);
        const uint* wr = Wq + ((size_t)(c * 4 + wv) * 64 + lane) * 8;
        uint4 w0 = *(const uint4*)(wr);
        uint4 w1 = *(const uint4*)(wr + 4);
        short8 bh, bl;
        unpack8(w0, w1, &bh, &bl);
        acc = __builtin_amdgcn_mfma_f32_32x32x16_bf16(ah, bh, acc, 0, 0, 0);
        acc = __builtin_amdgcn_mfma_f32_32x32x16_bf16(al, bh, acc, 0, 0, 0);
        acc = __builtin_amdgcn_mfma_f32_32x32x16_bf16(ah, bl, acc, 0, 0, 0);
    }
    const int col = wv * 32 + m31;
    const float bb = bias[col];
    #pragma unroll
    for (int reg = 0; reg < 16; ++reg) {
        int row = (reg & 3) + 8 * (reg >> 2) + 4 * half;
        gbuf[row * 129 + col] = fmaxf(acc[reg] + bb, 0.f);
    }
    __syncthreads();

    const int node = t >> 3;
    const int seg  = t & 7;
    const float* gr = gbuf + node * 129 + seg * 16;
    float a = 0.f;
    #pragma unroll
    for (int i = 0; i < 16; ++i) a += gr[i] * f2[seg * 16 + i];
    a += __shfl_down(a, 4, 8);
    a += __shfl_down(a, 2, 8);
    a += __shfl_down(a, 1, 8);
    if (seg == 0) out[r0 + node] = a + f2b[0];
}

// ---------------- merged prep: wprep + wfoldA + wfoldB + hist ---------------
// blocks [0,128): pack/swizzle c0_w2,c1_w2 ; [128,256): fold Wa ;
// [256,384): fold Wb ; [384,384+EB): dst histogram.
__global__ __launch_bounds__(256) void prep_kernel(
    const float* __restrict__ c0w2, const float* __restrict__ c1w2,
    const float* __restrict__ c1w1, const float* __restrict__ c0w3,
    const float* __restrict__ c0b3, const float* __restrict__ c1b1,
    const float* __restrict__ fw1,  const float* __restrict__ c1w3,
    const float* __restrict__ c1b3, const float* __restrict__ fb1,
    const int* __restrict__ dst, int* __restrict__ cnt,
    uint* __restrict__ wp, uint* __restrict__ p_Wa, uint* __restrict__ p_Wb,
    float* __restrict__ f_ba, float* __restrict__ f_bb)
{
    const int b = blockIdx.x;
    const int t = threadIdx.x;
    if (b < 128) {
        int i = b * 256 + t;                     // 32768 elems
        const float* src = (i < 16384) ? c0w2 : c1w2;
        int off = (i < 16384) ? 0 : 16384;
        int L = i - off;
        int o = L >> 7, k = L & 127;
        short hh, ll;
        splits(src[L], &hh, &ll);
        wp[off + wswz(o, k)] = ((uint)(unsigned short)hh << 16) | (uint)(unsigned short)ll;
    } else if (b < 384) {
        const bool isA = (b < 256);
        const int o = b - (isA ? 128 : 256);
        const float* A   = isA ? c1w1 : fw1;
        const float* B   = isA ? c0w3 : c1w3;
        const float* bi  = isA ? c0b3 : c1b3;
        const float* bo  = isA ? c1b1 : fb1;
        uint*  W  = isA ? p_Wa : p_Wb;
        float* bb = isA ? f_ba : f_bb;
        const float* Ar = A + o * 128;
        float s = 0.f;
        for (int j = 0; j < 128; ++j) s += Ar[j] * B[j * 256 + t];
        short hh, ll;
        splits(s, &hh, &ll);
        W[wswz(o, t)] = ((uint)(unsigned short)hh << 16) | (uint)(unsigned short)ll;
        if (t == 0) {
            float sb = 0.f;
            for (int j = 0; j < 128; ++j) sb += Ar[j] * bi[j];
            bb[o] = sb + bo[o];
        }
    } else {
        int e = (b - 384) * 256 + t;
        if (e < NE) atomicAdd(&cnt[dst[e]], 1);
    }
}

// ---------------- scans (unchanged) ----------------
__global__ __launch_bounds__(256) void scan1_kernel(
    const int* __restrict__ cnt, int* __restrict__ row_ptr,
    int* __restrict__ partials)
{
    __shared__ int s[256];
    const int t = threadIdx.x;
    const int i = blockIdx.x * 256 + t;
    int v = (i < NN) ? cnt[i] : 0;
    s[t] = v;
    __syncthreads();
    #pragma unroll
    for (int off = 1; off < 256; off <<= 1) {
        int x = (t >= off) ? s[t - off] : 0;
        __syncthreads();
        s[t] += x;
        __syncthreads();
    }
    if (i < NN) row_ptr[i] = s[t] - v;
    if (t == 255) partials[blockIdx.x] = s[255];
}

__global__ __launch_bounds__(256) void scan2_kernel(
    int* __restrict__ partials, int* __restrict__ row_ptr)
{
    __shared__ int s[256];
    const int t = threadIdx.x;
    int v = (t < SCAN_BLK) ? partials[t] : 0;
    s[t] = v;
    __syncthreads();
    #pragma unroll
    for (int off = 1; off < 256; off <<= 1) {
        int x = (t >= off) ? s[t - off] : 0;
        __syncthreads();
        s[t] += x;
        __syncthreads();
    }
    if (t < SCAN_BLK) partials[t] = s[t] - v;
    if (t == 255) row_ptr[NN] = s[255];
}

__global__ __launch_bounds__(256) void scan3_kernel(
    int* __restrict__ row_ptr, const int* __restrict__ partials)
{
    const int i = blockIdx.x * 256 + threadIdx.x;
    if (i < NN) row_ptr[i] += partials[blockIdx.x];
}

// ---------------- merged fill + embed ---------------------------------------
// blocks [0,EB): CSR fill ; [EB, EB+2500): K=11 embed, 16 rows/block.
__global__ __launch_bounds__(256) void fill_embed_kernel(
    const int* __restrict__ src, const int* __restrict__ dst,
    const int* __restrict__ row_ptr, int* __restrict__ pos,
    int* __restrict__ esrc,
    const float* __restrict__ x, const float* __restrict__ w1,
    const float* __restrict__ b1, __half* __restrict__ h0)
{
    const int b = blockIdx.x;
    const int t = threadIdx.x;
    if (b < EB) {
        int e = b * 256 + t;
        if (e < NE) {
            int d = dst[e];
            int p = row_ptr[d] + atomicAdd(&pos[d], 1);
            esrc[p] = src[e];
        }
    } else {
        __shared__ float xs[2][88];
        const int hf = t >> 7;               // 0/1
        const int m  = t & 127;
        const int r0 = (b - EB) * 16 + hf * 8;
        for (int i = m; i < 88; i += 128) {
            int r = i / 11, k = i - r * 11;
            xs[hf][i] = x[(size_t)(r0 + r) * 11 + k];
        }
        __syncthreads();
        float acc[8] = {};
        const float* Wm = w1 + m * 11;
        #pragma unroll
        for (int k = 0; k < 11; ++k) {
            float w = Wm[k];
            #pragma unroll
            for (int r = 0; r < 8; ++r) acc[r] += xs[hf][r * 11 + k] * w;
        }
        const float bias = b1[m];
        #pragma unroll
        for (int r = 0; r < 8; ++r) {
            float v = fmaxf(acc[r] + bias, 0.f);
            h0[(size_t)(r0 + r) * HID + m] = __float2half(v);
        }
    }
}

extern "C" void kernel_launch(void* const* d_in, const int* in_sizes, int n_in,
                              void* d_out, int out_size, void* d_ws, size_t ws_size,
                              hipStream_t stream)
{
    const float* x     = (const float*)d_in[0];
    const int*   eidx  = (const int*)d_in[1];
    const float* c0_w1 = (const float*)d_in[2],  *c0_b1 = (const float*)d_in[3];
    const float* c0_w2 = (const float*)d_in[4],  *c0_b2 = (const float*)d_in[5];
    const float* c0_w3 = (const float*)d_in[6],  *c0_b3 = (const float*)d_in[7];
    const float* c1_w1 = (const float*)d_in[8],  *c1_b1 = (const float*)d_in[9];
    const float* c1_w2 = (const float*)d_in[10], *c1_b2 = (const float*)d_in[11];
    const float* c1_w3 = (const float*)d_in[12], *c1_b3 = (const float*)d_in[13];
    const float* f_w1  = (const float*)d_in[14], *f_b1  = (const float*)d_in[15];
    const float* f_w2  = (const float*)d_in[16], *f_b2  = (const float*)d_in[17];
    const int* src = eidx;
    const int* dst = eidx + NE;
    float* out = (float*)d_out;

    const size_t BUF = (size_t)NN * HID;
    __half* bA = (__half*)d_ws;
    __half* bB = bA + BUF;
    __half* bC = bB + BUF;
    int* row_ptr  = (int*)(bC + BUF);        // NN+1
    int* cnt      = row_ptr + (NN + 1);      // NN (hist)
    int* pos      = cnt + NN;                // NN (fill cursor)
    int* esrc     = pos + NN;                // NE
    int* partials = esrc + NE;               // SCAN_BLK
    uint* wp      = (uint*)(partials + SCAN_BLK);

    uint* p_c0w2 = wp + 0;          // 16384
    uint* p_c1w2 = wp + 16384;      // 16384
    uint* p_Wa   = wp + 32768;      // 32768 (c1_w1 · c0_w3)
    uint* p_Wb   = wp + 65536;      // 32768 (f_w1 · c1_w3)
    float* f_ba  = (float*)(wp + 98304);  // 128
    float* f_bb  = f_ba + 128;            // 128

    const int nbl = (NN + 31) / 32;   // 1250

    // ---- prep (weights + hist) + CSR scan + fill/embed ----
    (void)hipMemsetAsync(cnt, 0, 2 * NN * sizeof(int), stream);   // cnt + pos
    prep_kernel<<<384 + EB, 256, 0, stream>>>(
        c0_w2, c1_w2, c1_w1, c0_w3, c0_b3, c1_b1,
        f_w1, c1_w3, c1_b3, f_b1, dst, cnt, wp, p_Wa, p_Wb, f_ba, f_bb);
    scan1_kernel<<<SCAN_BLK, 256, 0, stream>>>(cnt, row_ptr, partials);
    scan2_kernel<<<1, 256, 0, stream>>>(partials, row_ptr);
    scan3_kernel<<<SCAN_BLK, 256, 0, stream>>>(row_ptr, partials);
    fill_embed_kernel<<<EB + 2500, 256, 0, stream>>>(
        src, dst, row_ptr, pos, esrc, x, c0_w1, c0_b1, bA);       // h0 = bA

    // ---- conv0 ----
    fused_gather_lin_kernel<<<nbl, 256, 0, stream>>>(bA, row_ptr, esrc, p_c0w2, c0_b2, bB); // l1_0
    fused_gather_lin_kernel<<<nbl, 256, 0, stream>>>(bB, row_ptr, esrc, p_c0w2, c0_b2, bC); // l2_0
    lin32_kernel<2, true><<<nbl, 256, 0, stream>>>(bB, bC, p_Wa, f_ba, bA);                 // h1 (folded)

    // ---- conv1 ----
    fused_gather_lin_kernel<<<nbl, 256, 0, stream>>>(bA, row_ptr, esrc, p_c1w2, c1_b2, bB); // l1_1
    fused_gather_lin_kernel<<<nbl, 256, 0, stream>>>(bB, row_ptr, esrc, p_c1w2, c1_b2, bC); // l2_1
    cat_head_kernel<<<nbl, 256, 0, stream>>>(bB, bC, p_Wb, f_bb, f_w2, f_b2, out);          // folded tail
}

// Round 16
// 322.509 us; speedup vs baseline: 1.3875x; 1.0266x over previous
//
#include <hip/hip_runtime.h>
#include <hip/hip_fp16.h>

#define NN 40000
#define NE 640000
#define HID 128
#define SCAN_BLK ((NN + 255) / 256)   // 157
#define EB ((NE + 255) / 256)         // 2500

typedef __attribute__((ext_vector_type(8)))  short short8;
typedef __attribute__((ext_vector_type(4)))  short short4v;
typedef __attribute__((ext_vector_type(16))) float floatx16;
typedef unsigned int uint;

__device__ __forceinline__ short f2bf(float f) {
    union { float f; unsigned u; } c; c.f = f;
    unsigned u = c.u;
    unsigned r = (u + 0x7FFF + ((u >> 16) & 1)) >> 16;   // RNE
    return (short)r;
}
__device__ __forceinline__ float bf2f(short h) {
    union { unsigned u; float f; } c;
    c.u = ((unsigned)(unsigned short)h) << 16;
    return c.f;
}
__device__ __forceinline__ float2 h2f2(uint u) {
    union { uint u; __half2 h; } c; c.u = u;
    return __half22float2(c.h);
}
__device__ __forceinline__ void splits(float f, short* hi, short* lo) {
    short h = f2bf(f);
    *hi = h;
    *lo = f2bf(f - bf2f(h));
}
__device__ __forceinline__ void unpack8(uint4 a, uint4 b, short8* h, short8* l) {
    short8 H, L;
    H[0] = (short)(a.x >> 16); L[0] = (short)a.x;
    H[1] = (short)(a.y >> 16); L[1] = (short)a.y;
    H[2] = (short)(a.z >> 16); L[2] = (short)a.z;
    H[3] = (short)(a.w >> 16); L[3] = (short)a.w;
    H[4] = (short)(b.x >> 16); L[4] = (short)b.x;
    H[5] = (short)(b.y >> 16); L[5] = (short)b.y;
    H[6] = (short)(b.z >> 16); L[6] = (short)b.z;
    H[7] = (short)(b.w >> 16); L[7] = (short)b.w;
    *h = H; *l = L;
}

// W fragment swizzle (HW-verified r9-r15)
__device__ __forceinline__ int wswz(int o, int k) {
    int chunk = k >> 4, half = (k >> 3) & 1, j = k & 7;
    int ct = o >> 5, m31 = o & 31;
    int lane = half * 32 + m31;
    return (((chunk * 4 + ct) * 64 + lane) * 8 + j);
}

#define ACCH(u, A)                                      \
    { float2 f0 = h2f2(u.x), f1 = h2f2(u.y);            \
      A.x += f0.x; A.y += f0.y; A.z += f1.x; A.w += f1.y; }

// ---------------- fused gather + split-bf16 MFMA linear (fp16 activations) --
// out[n][:] = fp16( relu( W · (sum_{e: dst=n} h[src[e]]) + b ) ), 32 nodes/blk.
// Work-stealing lane-groups; 8 independent row loads in flight (request-bound
// regime after fp16 halved bytes/row — r15 post-mortem).
__global__ __launch_bounds__(256, 4) void fused_gather_lin_kernel(
    const __half* __restrict__ h, const int* __restrict__ row_ptr,
    const int* __restrict__ esrc, const uint* __restrict__ Wq,
    const float* __restrict__ bias, __half* __restrict__ out)
{
    __shared__ short sAh[4096];
    __shared__ short sAl[4096];
    __shared__ int   sCtr;
    const int t  = threadIdx.x;
    const int r0 = blockIdx.x * 32;
    const int c4 = t & 31;
    const int sub = c4 >> 1;
    const int j0  = (c4 & 1) * 4;
    const uint2* hp = (const uint2*)h;   // row = 32 uint2

    if (t == 0) sCtr = 0;
    __syncthreads();

    for (;;) {
        int n = 0;
        if ((t & 31) == 0) n = atomicAdd(&sCtr, 1);
        n = __shfl(n, 0, 32);
        if (n >= 32) break;
        const int node = r0 + n;
        const int lo = row_ptr[node], hi = row_ptr[node + 1];
        float4 a = make_float4(0,0,0,0), b = make_float4(0,0,0,0);
        float4 c = make_float4(0,0,0,0), d = make_float4(0,0,0,0);
        int e = lo;
        for (; e + 8 <= hi; e += 8) {
            int s0 = esrc[e],   s1 = esrc[e+1], s2 = esrc[e+2], s3 = esrc[e+3];
            int s4 = esrc[e+4], s5 = esrc[e+5], s6 = esrc[e+6], s7 = esrc[e+7];
            uint2 u0 = hp[(size_t)s0 * 32 + c4];
            uint2 u1 = hp[(size_t)s1 * 32 + c4];
            uint2 u2 = hp[(size_t)s2 * 32 + c4];
            uint2 u3 = hp[(size_t)s3 * 32 + c4];
            uint2 u4 = hp[(size_t)s4 * 32 + c4];
            uint2 u5 = hp[(size_t)s5 * 32 + c4];
            uint2 u6 = hp[(size_t)s6 * 32 + c4];
            uint2 u7 = hp[(size_t)s7 * 32 + c4];
            ACCH(u0, a); ACCH(u1, b); ACCH(u2, c); ACCH(u3, d);
            ACCH(u4, a); ACCH(u5, b); ACCH(u6, c); ACCH(u7, d);
        }
        for (; e + 4 <= hi; e += 4) {
            int s0 = esrc[e], s1 = esrc[e+1], s2 = esrc[e+2], s3 = esrc[e+3];
            uint2 u0 = hp[(size_t)s0 * 32 + c4];
            uint2 u1 = hp[(size_t)s1 * 32 + c4];
            uint2 u2 = hp[(size_t)s2 * 32 + c4];
            uint2 u3 = hp[(size_t)s3 * 32 + c4];
            ACCH(u0, a); ACCH(u1, b); ACCH(u2, c); ACCH(u3, d);
        }
        for (; e < hi; ++e) {
            int s0 = esrc[e];
            uint2 u0 = hp[(size_t)s0 * 32 + c4];
            ACCH(u0, a);
        }
        float vx = (a.x + b.x) + (c.x + d.x);
        float vy = (a.y + b.y) + (c.y + d.y);
        float vz = (a.z + b.z) + (c.z + d.z);
        float vw = (a.w + b.w) + (c.w + d.w);
        short4v Hq, Lq;
        short hh, ll;
        splits(vx, &hh, &ll); Hq.x = hh; Lq.x = ll;
        splits(vy, &hh, &ll); Hq.y = hh; Lq.y = ll;
        splits(vz, &hh, &ll); Hq.z = hh; Lq.z = ll;
        splits(vw, &hh, &ll); Hq.w = hh; Lq.w = ll;
        const int off = sub * 256 + n * 8 + j0;
        *(short4v*)(sAh + off) = Hq;
        *(short4v*)(sAl + off) = Lq;
    }
    __syncthreads();

    const int wv   = t >> 6;
    const int lane = t & 63;
    const int m31  = lane & 31;
    const int half = lane >> 5;
    floatx16 acc;
    #pragma unroll
    for (int i = 0; i < 16; ++i) acc[i] = 0.f;
    #pragma unroll
    for (int c = 0; c < 8; ++c) {
        short8 ah = *(const short8*)(sAh + (c * 2 + half) * 256 + m31 * 8);
        short8 al = *(const short8*)(sAl + (c * 2 + half) * 256 + m31 * 8);
        const uint* wr = Wq + ((size_t)(c * 4 + wv) * 64 + lane) * 8;
        uint4 w0 = *(const uint4*)(wr);
        uint4 w1 = *(const uint4*)(wr + 4);
        short8 bh, bl;
        unpack8(w0, w1, &bh, &bl);
        acc = __builtin_amdgcn_mfma_f32_32x32x16_bf16(ah, bh, acc, 0, 0, 0);
        acc = __builtin_amdgcn_mfma_f32_32x32x16_bf16(al, bh, acc, 0, 0, 0);
        acc = __builtin_amdgcn_mfma_f32_32x32x16_bf16(ah, bl, acc, 0, 0, 0);
    }
    const int col = wv * 32 + m31;
    const float bb = bias[col];
    #pragma unroll
    for (int reg = 0; reg < 16; ++reg) {
        int row = (reg & 3) + 8 * (reg >> 2) + 4 * half;
        float v = fmaxf(acc[reg] + bb, 0.f);
        out[(size_t)(r0 + row) * HID + col] = __float2half(v);
    }
}

// ---------------- standalone split-bf16 MFMA linear, 32-row tiles -----------
template<int PHASES, bool RELU>
__global__ __launch_bounds__(256, 4) void lin32_kernel(
    const __half* __restrict__ X0, const __half* __restrict__ X1,
    const uint* __restrict__ Wq, const float* __restrict__ bias,
    __half* __restrict__ out)
{
    __shared__ short sAh[PHASES * 4096];
    __shared__ short sAl[PHASES * 4096];
    const int t  = threadIdx.x;
    const int r0 = blockIdx.x * 32;

    #pragma unroll
    for (int i = 0; i < PHASES * 4; ++i) {
        int v = t + 256 * i;
        const __half* Xp = (PHASES == 2 && v >= 1024) ? X1 : X0;
        int vv  = v & 1023;
        int row = vv >> 5, q = vv & 31;
        uint2 u = *(const uint2*)(Xp + (size_t)(r0 + row) * 128 + q * 4);
        float2 f0 = h2f2(u.x), f1 = h2f2(u.y);
        int kk  = ((PHASES == 2) ? (v >> 10) * 128 : 0) + q * 4;
        int off = (kk >> 3) * 256 + row * 8 + (q & 1) * 4;
        short4v hi, lo;
        short hh, ll;
        splits(f0.x, &hh, &ll); hi.x = hh; lo.x = ll;
        splits(f0.y, &hh, &ll); hi.y = hh; lo.y = ll;
        splits(f1.x, &hh, &ll); hi.z = hh; lo.z = ll;
        splits(f1.y, &hh, &ll); hi.w = hh; lo.w = ll;
        *(short4v*)(sAh + off) = hi;
        *(short4v*)(sAl + off) = lo;
    }
    __syncthreads();

    const int wv   = t >> 6;
    const int lane = t & 63;
    const int m31  = lane & 31;
    const int half = lane >> 5;
    floatx16 acc;
    #pragma unroll
    for (int i = 0; i < 16; ++i) acc[i] = 0.f;
    #pragma unroll
    for (int c = 0; c < PHASES * 8; ++c) {
        short8 ah = *(const short8*)(sAh + (c * 2 + half) * 256 + m31 * 8);
        short8 al = *(const short8*)(sAl + (c * 2 + half) * 256 + m31 * 8);
        const uint* wr = Wq + ((size_t)(c * 4 + wv) * 64 + lane) * 8;
        uint4 w0 = *(const uint4*)(wr);
        uint4 w1 = *(const uint4*)(wr + 4);
        short8 bh, bl;
        unpack8(w0, w1, &bh, &bl);
        acc = __builtin_amdgcn_mfma_f32_32x32x16_bf16(ah, bh, acc, 0, 0, 0);
        acc = __builtin_amdgcn_mfma_f32_32x32x16_bf16(al, bh, acc, 0, 0, 0);
        acc = __builtin_amdgcn_mfma_f32_32x32x16_bf16(ah, bl, acc, 0, 0, 0);
    }
    const int col = wv * 32 + m31;
    const float bb = bias[col];
    #pragma unroll
    for (int reg = 0; reg < 16; ++reg) {
        int row = (reg & 3) + 8 * (reg >> 2) + 4 * half;
        float v = acc[reg] + bb;
        if (RELU) v = fmaxf(v, 0.f);
        out[(size_t)(r0 + row) * HID + col] = __float2half(v);
    }
}

// ---------------- cat-GEMM (Wb) + fused head --------------------------------
__global__ __launch_bounds__(256, 3) void cat_head_kernel(
    const __half* __restrict__ X0, const __half* __restrict__ X1,
    const uint* __restrict__ Wq, const float* __restrict__ bias,
    const float* __restrict__ f2, const float* __restrict__ f2b,
    float* __restrict__ out)
{
    __shared__ short sAh[8192];
    __shared__ short sAl[8192];
    __shared__ float gbuf[32 * 129];
    const int t  = threadIdx.x;
    const int r0 = blockIdx.x * 32;

    #pragma unroll
    for (int i = 0; i < 8; ++i) {
        int v = t + 256 * i;
        const __half* Xp = (v >= 1024) ? X1 : X0;
        int vv  = v & 1023;
        int row = vv >> 5, q = vv & 31;
        uint2 u = *(const uint2*)(Xp + (size_t)(r0 + row) * 128 + q * 4);
        float2 f0 = h2f2(u.x), f1 = h2f2(u.y);
        int kk  = (v >> 10) * 128 + q * 4;
        int off = (kk >> 3) * 256 + row * 8 + (q & 1) * 4;
        short4v hi, lo;
        short hh, ll;
        splits(f0.x, &hh, &ll); hi.x = hh; lo.x = ll;
        splits(f0.y, &hh, &ll); hi.y = hh; lo.y = ll;
        splits(f1.x, &hh, &ll); hi.z = hh; lo.z = ll;
        splits(f1.y, &hh, &ll); hi.w = hh; lo.w = ll;
        *(short4v*)(sAh + off) = hi;
        *(short4v*)(sAl + off) = lo;
    }
    __syncthreads();

    const int wv   = t >> 6;
    const int lane = t & 63;
    const int m31  = lane & 31;
    const int half = lane >> 5;
    floatx16 acc;
    #pragma unroll
    for (int i = 0; i < 16; ++i) acc[i] = 0.f;
    #pragma unroll
    for (int c = 0; c < 16; ++c) {
        short8 ah = *(const short8*)(sAh + (c * 2 + half) * 256 + m31 * 8);
        short8 al = *(const short8*)(sAl + (c * 2 + half) * 256 + m31 * 8);
        const uint* wr = Wq + ((size_t)(c * 4 + wv) * 64 + lane) * 8;
        uint4 w0 = *(const uint4*)(wr);
        uint4 w1 = *(const uint4*)(wr + 4);
        short8 bh, bl;
        unpack8(w0, w1, &bh, &bl);
        acc = __builtin_amdgcn_mfma_f32_32x32x16_bf16(ah, bh, acc, 0, 0, 0);
        acc = __builtin_amdgcn_mfma_f32_32x32x16_bf16(al, bh, acc, 0, 0, 0);
        acc = __builtin_amdgcn_mfma_f32_32x32x16_bf16(ah, bl, acc, 0, 0, 0);
    }
    const int col = wv * 32 + m31;
    const float bb = bias[col];
    #pragma unroll
    for (int reg = 0; reg < 16; ++reg) {
        int row = (reg & 3) + 8 * (reg >> 2) + 4 * half;
        gbuf[row * 129 + col] = fmaxf(acc[reg] + bb, 0.f);
    }
    __syncthreads();

    const int node = t >> 3;
    const int seg  = t & 7;
    const float* gr = gbuf + node * 129 + seg * 16;
    float a = 0.f;
    #pragma unroll
    for (int i = 0; i < 16; ++i) a += gr[i] * f2[seg * 16 + i];
    a += __shfl_down(a, 4, 8);
    a += __shfl_down(a, 2, 8);
    a += __shfl_down(a, 1, 8);
    if (seg == 0) out[r0 + node] = a + f2b[0];
}

// ---------------- merged prep: wprep + wfoldA + wfoldB + hist ---------------
__global__ __launch_bounds__(256) void prep_kernel(
    const float* __restrict__ c0w2, const float* __restrict__ c1w2,
    const float* __restrict__ c1w1, const float* __restrict__ c0w3,
    const float* __restrict__ c0b3, const float* __restrict__ c1b1,
    const float* __restrict__ fw1,  const float* __restrict__ c1w3,
    const float* __restrict__ c1b3, const float* __restrict__ fb1,
    const int* __restrict__ dst, int* __restrict__ cnt,
    uint* __restrict__ wp, uint* __restrict__ p_Wa, uint* __restrict__ p_Wb,
    float* __restrict__ f_ba, float* __restrict__ f_bb)
{
    const int b = blockIdx.x;
    const int t = threadIdx.x;
    if (b < 128) {
        int i = b * 256 + t;
        const float* src = (i < 16384) ? c0w2 : c1w2;
        int off = (i < 16384) ? 0 : 16384;
        int L = i - off;
        int o = L >> 7, k = L & 127;
        short hh, ll;
        splits(src[L], &hh, &ll);
        wp[off + wswz(o, k)] = ((uint)(unsigned short)hh << 16) | (uint)(unsigned short)ll;
    } else if (b < 384) {
        const bool isA = (b < 256);
        const int o = b - (isA ? 128 : 256);
        const float* A   = isA ? c1w1 : fw1;
        const float* B   = isA ? c0w3 : c1w3;
        const float* bi  = isA ? c0b3 : c1b3;
        const float* bo  = isA ? c1b1 : fb1;
        uint*  W  = isA ? p_Wa : p_Wb;
        float* bb = isA ? f_ba : f_bb;
        const float* Ar = A + o * 128;
        float s = 0.f;
        for (int j = 0; j < 128; ++j) s += Ar[j] * B[j * 256 + t];
        short hh, ll;
        splits(s, &hh, &ll);
        W[wswz(o, t)] = ((uint)(unsigned short)hh << 16) | (uint)(unsigned short)ll;
        if (t == 0) {
            float sb = 0.f;
            for (int j = 0; j < 128; ++j) sb += Ar[j] * bi[j];
            bb[o] = sb + bo[o];
        }
    } else {
        int e = (b - 384) * 256 + t;
        if (e < NE) atomicAdd(&cnt[dst[e]], 1);
    }
}

// ---------------- scans ----------------
__global__ __launch_bounds__(256) void scan1_kernel(
    const int* __restrict__ cnt, int* __restrict__ row_ptr,
    int* __restrict__ partials)
{
    __shared__ int s[256];
    const int t = threadIdx.x;
    const int i = blockIdx.x * 256 + t;
    int v = (i < NN) ? cnt[i] : 0;
    s[t] = v;
    __syncthreads();
    #pragma unroll
    for (int off = 1; off < 256; off <<= 1) {
        int x = (t >= off) ? s[t - off] : 0;
        __syncthreads();
        s[t] += x;
        __syncthreads();
    }
    if (i < NN) row_ptr[i] = s[t] - v;
    if (t == 255) partials[blockIdx.x] = s[255];
}

__global__ __launch_bounds__(256) void scan2_kernel(
    int* __restrict__ partials, int* __restrict__ row_ptr)
{
    __shared__ int s[256];
    const int t = threadIdx.x;
    int v = (t < SCAN_BLK) ? partials[t] : 0;
    s[t] = v;
    __syncthreads();
    #pragma unroll
    for (int off = 1; off < 256; off <<= 1) {
        int x = (t >= off) ? s[t - off] : 0;
        __syncthreads();
        s[t] += x;
        __syncthreads();
    }
    if (t < SCAN_BLK) partials[t] = s[t] - v;
    if (t == 255) row_ptr[NN] = s[255];
}

__global__ __launch_bounds__(256) void scan3_kernel(
    int* __restrict__ row_ptr, const int* __restrict__ partials)
{
    const int i = blockIdx.x * 256 + threadIdx.x;
    if (i < NN) row_ptr[i] += partials[blockIdx.x];
}

// ---------------- merged fill + embed ---------------------------------------
__global__ __launch_bounds__(256) void fill_embed_kernel(
    const int* __restrict__ src, const int* __restrict__ dst,
    const int* __restrict__ row_ptr, int* __restrict__ pos,
    int* __restrict__ esrc,
    const float* __restrict__ x, const float* __restrict__ w1,
    const float* __restrict__ b1, __half* __restrict__ h0)
{
    const int b = blockIdx.x;
    const int t = threadIdx.x;
    if (b < EB) {
        int e = b * 256 + t;
        if (e < NE) {
            int d = dst[e];
            int p = row_ptr[d] + atomicAdd(&pos[d], 1);
            esrc[p] = src[e];
        }
    } else {
        __shared__ float xs[2][88];
        const int hf = t >> 7;
        const int m  = t & 127;
        const int r0 = (b - EB) * 16 + hf * 8;
        for (int i = m; i < 88; i += 128) {
            int r = i / 11, k = i - r * 11;
            xs[hf][i] = x[(size_t)(r0 + r) * 11 + k];
        }
        __syncthreads();
        float acc[8] = {};
        const float* Wm = w1 + m * 11;
        #pragma unroll
        for (int k = 0; k < 11; ++k) {
            float w = Wm[k];
            #pragma unroll
            for (int r = 0; r < 8; ++r) acc[r] += xs[hf][r * 11 + k] * w;
        }
        const float bias = b1[m];
        #pragma unroll
        for (int r = 0; r < 8; ++r) {
            float v = fmaxf(acc[r] + bias, 0.f);
            h0[(size_t)(r0 + r) * HID + m] = __float2half(v);
        }
    }
}

extern "C" void kernel_launch(void* const* d_in, const int* in_sizes, int n_in,
                              void* d_out, int out_size, void* d_ws, size_t ws_size,
                              hipStream_t stream)
{
    const float* x     = (const float*)d_in[0];
    const int*   eidx  = (const int*)d_in[1];
    const float* c0_w1 = (const float*)d_in[2],  *c0_b1 = (const float*)d_in[3];
    const float* c0_w2 = (const float*)d_in[4],  *c0_b2 = (const float*)d_in[5];
    const float* c0_w3 = (const float*)d_in[6],  *c0_b3 = (const float*)d_in[7];
    const float* c1_w1 = (const float*)d_in[8],  *c1_b1 = (const float*)d_in[9];
    const float* c1_w2 = (const float*)d_in[10], *c1_b2 = (const float*)d_in[11];
    const float* c1_w3 = (const float*)d_in[12], *c1_b3 = (const float*)d_in[13];
    const float* f_w1  = (const float*)d_in[14], *f_b1  = (const float*)d_in[15];
    const float* f_w2  = (const float*)d_in[16], *f_b2  = (const float*)d_in[17];
    const int* src = eidx;
    const int* dst = eidx + NE;
    float* out = (float*)d_out;

    const size_t BUF = (size_t)NN * HID;
    __half* bA = (__half*)d_ws;
    __half* bB = bA + BUF;
    __half* bC = bB + BUF;
    int* row_ptr  = (int*)(bC + BUF);        // NN+1
    int* cnt      = row_ptr + (NN + 1);      // NN (hist)
    int* pos      = cnt + NN;                // NN (fill cursor)
    int* esrc     = pos + NN;                // NE
    int* partials = esrc + NE;               // SCAN_BLK
    uint* wp      = (uint*)(partials + SCAN_BLK);

    uint* p_c0w2 = wp + 0;          // 16384
    uint* p_c1w2 = wp + 16384;      // 16384
    uint* p_Wa   = wp + 32768;      // 32768 (c1_w1 · c0_w3)
    uint* p_Wb   = wp + 65536;      // 32768 (f_w1 · c1_w3)
    float* f_ba  = (float*)(wp + 98304);  // 128
    float* f_bb  = f_ba + 128;            // 128

    const int nbl = (NN + 31) / 32;   // 1250

    // ---- prep (weights + hist) + CSR scan + fill/embed ----
    (void)hipMemsetAsync(cnt, 0, 2 * NN * sizeof(int), stream);   // cnt + pos
    prep_kernel<<<384 + EB, 256, 0, stream>>>(
        c0_w2, c1_w2, c1_w1, c0_w3, c0_b3, c1_b1,
        f_w1, c1_w3, c1_b3, f_b1, dst, cnt, wp, p_Wa, p_Wb, f_ba, f_bb);
    scan1_kernel<<<SCAN_BLK, 256, 0, stream>>>(cnt, row_ptr, partials);
    scan2_kernel<<<1, 256, 0, stream>>>(partials, row_ptr);
    scan3_kernel<<<SCAN_BLK, 256, 0, stream>>>(row_ptr, partials);
    fill_embed_kernel<<<EB + 2500, 256, 0, stream>>>(
        src, dst, row_ptr, pos, esrc, x, c0_w1, c0_b1, bA);       // h0 = bA

    // ---- conv0 ----
    fused_gather_lin_kernel<<<nbl, 256, 0, stream>>>(bA, row_ptr, esrc, p_c0w2, c0_b2, bB); // l1_0
    fused_gather_lin_kernel<<<nbl, 256, 0, stream>>>(bB, row_ptr, esrc, p_c0w2, c0_b2, bC); // l2_0
    lin32_kernel<2, true><<<nbl, 256, 0, stream>>>(bB, bC, p_Wa, f_ba, bA);                 // h1 (folded)

    // ---- conv1 ----
    fused_gather_lin_kernel<<<nbl, 256, 0, stream>>>(bA, row_ptr, esrc, p_c1w2, c1_b2, bB); // l1_1
    fused_gather_lin_kernel<<<nbl, 256, 0, stream>>>(bB, row_ptr, esrc, p_c1w2, c1_b2, bC); // l2_1
    cat_head_kernel<<<nbl, 256, 0, stream>>>(bB, bC, p_Wb, f_bb, f_w2, f_b2, out);          // folded tail
}